// Round 1
// 90.582 us; speedup vs baseline: 1.0082x; 1.0082x over previous
//
#include <hip/hip_runtime.h>
#include <type_traits>

typedef short bf16x8 __attribute__((ext_vector_type(8)));
typedef float f32x4 __attribute__((ext_vector_type(4)));

// ---------------- problem constants ----------------
constexpr int Hh = 14, Ww = 14, Cc = 512, Bb = 512, NR = 70, PadR = 80;

// ---------------- constexpr replication of _crop_boxes ----------------
struct Box { int y1, y2, x1, x2; };

constexpr double cfloor(double v) { return (double)(long long)v; }  // v >= 0 only
constexpr double cround(double v) {  // np.round: half-to-even
    double f = cfloor(v);
    double fr = v - f;
    if (fr > 0.5) return f + 1.0;
    if (fr < 0.5) return f;
    return (((long long)f) & 1LL) ? f + 1.0 : f;
}

struct BoxArr { Box b[NR]; };

constexpr BoxArr make_boxes() {
    BoxArr out{};
    double rx_[14] = {}, ry_[14] = {}, wl_[14] = {};
    int nr = 0;
    for (int l = 1; l <= 3; ++l) {
        double wl  = cfloor(2.0 * 14.0 / (double)(l + 1));
        double wl2 = cfloor(wl / 2.0 - 1.0);
        double bb  = (l > 1) ? (14.0 - wl) / (double)(l - 1) : 0.0;
        double cen[3] = {};
        for (int k = 0; k < l; ++k) cen[k] = cfloor(wl2 + (double)k * bb) - wl2;
        for (int i = 0; i < l; ++i)
            for (int j = 0; j < l; ++j) { rx_[nr] = cen[j]; ry_[nr] = cen[i]; wl_[nr] = wl; ++nr; }
    }
    int nb = 0;
    for (int r = 0; r < nr; ++r) {
        for (int p = 1; p <= 2; ++p) {
            double len = wl_[r] / (double)p;
            for (int ix = 0; ix < p; ++ix)
                for (int jy = 0; jy < p; ++jy) {
                    int x1 = (int)cround(rx_[r] + ix * len);
                    int x2 = (int)cround(rx_[r] + ix * len + len);
                    int y1 = (int)cround(ry_[r] + jy * len);
                    int y2 = (int)cround(ry_[r] + jy * len + len);
                    out.b[nb] = Box{y1, y2, x1, x2};
                    ++nb;
                }
        }
    }
    return out;
}
constexpr BoxArr BOXES = make_boxes();

// distinct x-interval dedup
struct Meta { int nxi; int xlo[32]; int xhi[32]; int xid[NR]; };
constexpr Meta make_meta() {
    Meta m{};
    m.nxi = 0;
    for (int r = 0; r < NR; ++r) {
        int lo = BOXES.b[r].x1, hi = BOXES.b[r].x2, id = -1;
        for (int i = 0; i < m.nxi; ++i) if (m.xlo[i] == lo && m.xhi[i] == hi) { id = i; break; }
        if (id < 0) { id = m.nxi; m.xlo[id] = lo; m.xhi[id] = hi; m.nxi++; }
        m.xid[r] = id;
    }
    return m;
}
constexpr Meta MT = make_meta();
constexpr int NXI = MT.nxi;
static_assert(NXI == 14, "expected 14 distinct x-intervals");

__device__ __forceinline__ ushort f2bf(float f) {  // RNE float->bf16 (finite; -inf ok)
    union { float f; unsigned u; } v; v.f = f;
    unsigned r = v.u + 0x7FFFu + ((v.u >> 16) & 1u);
    return (ushort)(r >> 16);
}
__device__ __forceinline__ float bf2f(ushort u) {
    union { unsigned u; float f; } v; v.u = ((unsigned)u) << 16;
    return v.f;
}

// swizzled index into m_s[80][512]: 16B slots XOR'd by row&7 (matches GEMM read)
__device__ __forceinline__ int midx(int r, int c) {
    return r * Cc + (((c >> 3) ^ (r & 7)) << 3) + (c & 7);
}

// ---------------- kernel 0: W fp32 -> bf16 ----------------
__global__ __launch_bounds__(256) void k_convw(const float* __restrict__ w,
                                               ushort* __restrict__ o) {
    int i = (blockIdx.x * 256 + threadIdx.x) * 4;
    float4 f = *(const float4*)&w[i];
    ushort4 u;
    u.x = f2bf(f.x); u.y = f2bf(f.y); u.z = f2bf(f.z); u.w = f2bf(f.w);
    *(ushort4*)&o[i] = u;
}

// ---------------- fully fused, 1024-thread version ----------------
// 16 waves/block -> 4 waves/SIMD (vs 2 before). Per-thread footprint halved
// everywhere so combined VGPR+AGPR <= 128 (enforced by __launch_bounds__).
__global__ __launch_bounds__(1024, 4) void k_fused(const float* __restrict__ x,
                                                   const ushort* __restrict__ wbf,
                                                   const float* __restrict__ bias,
                                                   float* __restrict__ out) {
    __shared__ __align__(16) ushort m_s[PadR * Cc];          // 80 KB, XOR-swizzled
    __shared__ __align__(16) union UU {
        ushort ims[Hh * NXI * 128];                          // 50 KB (pool passes)
        struct {                                             // epilogue scratch (aliased)
            float rowss[PadR][16];
            float rns[PadR];
            float y_s[Cc];
            float red2[8];
        } e;
    } u;
    __shared__ float ss_s[PadR];
    __shared__ float rnm[PadR];

    const int b = blockIdx.x;
    const int tid = threadIdx.x;
    const int lane = tid & 63;
    const int wv = tid >> 6;                // 0..15
    const int l15 = lane & 15, lhi = lane >> 4;

    // zero pad rows of m_s (rows 70..79: 2560 uints) and tail of ss_s
    {
        uint* z = (uint*)&m_s[70 * Cc];
        z[tid] = 0;
        z[tid + 1024] = 0;
        if (tid < 512) z[tid + 2048] = 0;
        if (tid >= 70 && tid < PadR) ss_s[tid] = 0.f;
    }

    float ssacc[5];
    #pragma unroll
    for (int i = 0; i < 5; ++i) ssacc[i] = 0.f;

    const int q2 = tid & 63;                 // channel-pair lane within 128-ch pass
    const int hA = wv;                       // one row per wave (14..15 idle)
    const int c2 = tid & 63;                 // channel pair within 128 (phase B)

    for (int cg = 0; cg < 4; ++cg) {
        // ---- phase A: one row per wave, 14 independent float2 loads/thread ----
        if (hA < Hh) {
            const float2* xq = (const float2*)(x + (size_t)b * Hh * Ww * Cc
                                               + (size_t)hA * Ww * Cc + cg * 128 + q2 * 2);
            float2 row[Ww];
            #pragma unroll
            for (int w = 0; w < Ww; ++w) row[w] = xq[w * (Cc / 2)];
            #pragma unroll
            for (int xi = 0; xi < NXI; ++xi) {
                float2 mm = row[MT.xlo[xi]];
                #pragma unroll
                for (int w = MT.xlo[xi] + 1; w < MT.xhi[xi]; ++w) {
                    mm.x = fmaxf(mm.x, row[w].x); mm.y = fmaxf(mm.y, row[w].y);
                }
                ushort2 o;
                o.x = f2bf(mm.x); o.y = f2bf(mm.y);
                *(ushort2*)&u.ims[(hA * NXI + xi) * 128 + q2 * 2] = o;
            }
        }
        __syncthreads();

        // ---- phase B: y-fold, 14 wave-groups x exactly 5 boxes each ----
        auto fold = [&](auto GC) {
            constexpr int G = GC.value;
            #pragma unroll
            for (int i = 0; i < 5; ++i) {                    // rr = G*5+i < 70 always
                float m0 = -INFINITY, m1 = -INFINITY;
                #pragma unroll
                for (int h = BOXES.b[G * 5 + i].y1; h < BOXES.b[G * 5 + i].y2; ++h) {
                    ushort2 t2 = *(const ushort2*)
                        &u.ims[(h * NXI + MT.xid[G * 5 + i]) * 128 + 2 * c2];
                    m0 = fmaxf(m0, bf2f(t2.x)); m1 = fmaxf(m1, bf2f(t2.y));
                }
                ushort2 o; o.x = f2bf(m0); o.y = f2bf(m1);
                *(ushort2*)&m_s[midx(G * 5 + i, cg * 128 + 2 * c2)] = o;
                ssacc[i] += m0 * m0 + m1 * m1;
            }
        };
        if      (wv == 0)  fold(std::integral_constant<int, 0>{});
        else if (wv == 1)  fold(std::integral_constant<int, 1>{});
        else if (wv == 2)  fold(std::integral_constant<int, 2>{});
        else if (wv == 3)  fold(std::integral_constant<int, 3>{});
        else if (wv == 4)  fold(std::integral_constant<int, 4>{});
        else if (wv == 5)  fold(std::integral_constant<int, 5>{});
        else if (wv == 6)  fold(std::integral_constant<int, 6>{});
        else if (wv == 7)  fold(std::integral_constant<int, 7>{});
        else if (wv == 8)  fold(std::integral_constant<int, 8>{});
        else if (wv == 9)  fold(std::integral_constant<int, 9>{});
        else if (wv == 10) fold(std::integral_constant<int, 10>{});
        else if (wv == 11) fold(std::integral_constant<int, 11>{});
        else if (wv == 12) fold(std::integral_constant<int, 12>{});
        else if (wv == 13) fold(std::integral_constant<int, 13>{});
        __syncthreads();                      // ims consumed before next pass
    }

    // ---- publish SS (one butterfly per box), compute rnm ----
    #pragma unroll
    for (int i = 0; i < 5; ++i) {
        float s = ssacc[i];
        s += __shfl_xor(s, 1);  s += __shfl_xor(s, 2);  s += __shfl_xor(s, 4);
        s += __shfl_xor(s, 8);  s += __shfl_xor(s, 16); s += __shfl_xor(s, 32);
        if (lane == 0 && wv < 14) ss_s[wv * 5 + i] = s;
    }
    __syncthreads();
    if (tid < PadR) rnm[tid] = 1.f / fmaxf(sqrtf(ss_s[tid]), 1e-12f);
    __syncthreads();

    // ---- GEMM: t[80][512] = m * W^T; per-wave tile 80x32 (acc[5][2]) ----
    f32x4 acc[5][2];
    #pragma unroll
    for (int mi = 0; mi < 5; ++mi)
        #pragma unroll
        for (int ni = 0; ni < 2; ++ni) acc[mi][ni] = (f32x4){0.f, 0.f, 0.f, 0.f};

    auto loadB = [&](bf16x8 (&bf)[2][2], int k0) {
        #pragma unroll
        for (int ni = 0; ni < 2; ++ni)
            #pragma unroll
            for (int kh = 0; kh < 2; ++kh)
                bf[ni][kh] = *(const bf16x8*)(wbf + (size_t)(wv * 32 + ni * 16 + l15) * Cc
                                              + k0 + kh * 32 + lhi * 8);
    };

    bf16x8 bfc[2][2], bfn[2][2];
    loadB(bfc, 0);
    #pragma unroll
    for (int ks = 0; ks < 8; ++ks) {
        if (ks < 7) loadB(bfn, (ks + 1) * 64);
        #pragma unroll
        for (int kh = 0; kh < 2; ++kh) {
            bf16x8 af[5];
            #pragma unroll
            for (int mi = 0; mi < 5; ++mi) {
                int row = mi * 16 + l15;
                int slot = (ks * 8 + kh * 4 + lhi) ^ (row & 7);
                af[mi] = *(const bf16x8*)&m_s[row * Cc + slot * 8];
            }
            #pragma unroll
            for (int mi = 0; mi < 5; ++mi)
                #pragma unroll
                for (int ni = 0; ni < 2; ++ni)
                    acc[mi][ni] = __builtin_amdgcn_mfma_f32_16x16x32_bf16(
                        af[mi], bfc[ni][kh], acc[mi][ni], 0, 0, 0);
        }
        #pragma unroll
        for (int ni = 0; ni < 2; ++ni)
            #pragma unroll
            for (int kh = 0; kh < 2; ++kh) bfc[ni][kh] = bfn[ni][kh];
    }
    // no barrier needed: epilogue scratch aliases ims only (last read before the
    // final pass barrier); m_s is not aliased.

    // ---- fused epilogue: deferred A-norm + bias, row-norm, sum, final norm ----
    float bia[2];
    #pragma unroll
    for (int ni = 0; ni < 2; ++ni) bia[ni] = bias[wv * 32 + ni * 16 + l15];
    float rm[5][4];
    #pragma unroll
    for (int mi = 0; mi < 5; ++mi)
        #pragma unroll
        for (int j = 0; j < 4; ++j) rm[mi][j] = rnm[mi * 16 + lhi * 4 + j];
    #pragma unroll
    for (int mi = 0; mi < 5; ++mi)
        #pragma unroll
        for (int ni = 0; ni < 2; ++ni)
            #pragma unroll
            for (int j = 0; j < 4; ++j)
                acc[mi][ni][j] = fmaf(acc[mi][ni][j], rm[mi][j], bia[ni]);

    #pragma unroll
    for (int mi = 0; mi < 5; ++mi)
        #pragma unroll
        for (int j = 0; j < 4; ++j) {
            float s = 0.f;
            #pragma unroll
            for (int ni = 0; ni < 2; ++ni) s += acc[mi][ni][j] * acc[mi][ni][j];
            s += __shfl_xor(s, 1); s += __shfl_xor(s, 2);
            s += __shfl_xor(s, 4); s += __shfl_xor(s, 8);
            if (l15 == 0) u.e.rowss[mi * 16 + lhi * 4 + j][wv] = s;
        }
    __syncthreads();
    if (tid < PadR) {
        float s = 0.f;
        #pragma unroll
        for (int w16 = 0; w16 < 16; ++w16) s += u.e.rowss[tid][w16];
        u.e.rns[tid] = 1.f / fmaxf(sqrtf(s), 1e-12f);
    }
    __syncthreads();

    float ys[2] = {0.f, 0.f};
    #pragma unroll
    for (int mi = 0; mi < 5; ++mi)
        #pragma unroll
        for (int j = 0; j < 4; ++j) {
            int row = mi * 16 + lhi * 4 + j;
            float w = (row < NR) ? u.e.rns[row] : 0.f;   // skip pad rows
            #pragma unroll
            for (int ni = 0; ni < 2; ++ni) ys[ni] = fmaf(acc[mi][ni][j], w, ys[ni]);
        }
    #pragma unroll
    for (int ni = 0; ni < 2; ++ni) {
        ys[ni] += __shfl_xor(ys[ni], 16);
        ys[ni] += __shfl_xor(ys[ni], 32);
    }
    if (lane < 16)
        #pragma unroll
        for (int ni = 0; ni < 2; ++ni) u.e.y_s[wv * 32 + ni * 16 + lane] = ys[ni];
    __syncthreads();

    float yv = 0.f;
    if (tid < Cc) {
        yv = u.e.y_s[tid];
        float s2 = yv * yv;
        s2 += __shfl_xor(s2, 1);  s2 += __shfl_xor(s2, 2);  s2 += __shfl_xor(s2, 4);
        s2 += __shfl_xor(s2, 8);  s2 += __shfl_xor(s2, 16); s2 += __shfl_xor(s2, 32);
        if (lane == 0) u.e.red2[wv] = s2;
    }
    __syncthreads();
    if (tid < Cc) {
        float tot = 0.f;
        #pragma unroll
        for (int w8 = 0; w8 < 8; ++w8) tot += u.e.red2[w8];
        out[(size_t)b * Cc + tid] = yv / fmaxf(sqrtf(tot), 1e-12f);
    }
}

// ---------------- launch ----------------
extern "C" void kernel_launch(void* const* d_in, const int* in_sizes, int n_in,
                              void* d_out, int out_size, void* d_ws, size_t ws_size,
                              hipStream_t stream) {
    const float* x  = (const float*)d_in[0];
    const float* pw = (const float*)d_in[1];
    const float* pb = (const float*)d_in[2];
    float* out = (float*)d_out;

    ushort* wbf = (ushort*)d_ws;                          // 512x512 bf16 = 0.5 MB

    k_convw<<<dim3(256), dim3(256), 0, stream>>>(pw, wbf);
    k_fused<<<dim3(Bb), dim3(1024), 0, stream>>>(x, wbf, pb, out);
}